// Round 1
// baseline (945.590 us; speedup 1.0000x reference)
//
#include <hip/hip_runtime.h>

#define T_STEPS 512
#define NIN     4
#define HID     64
#define NPROJ   49
#define NG      256   // 4*HID
#define XCH     64    // x-chunk timesteps staged in LDS

// One workgroup (256 threads) owns one batch element for the full T loop.
// Thread tid owns gate tid: W_hh row + W_ih row + bias live in registers.
// h (49), gates (256), h_full (64) are exchanged through LDS each timestep.
__global__ __launch_bounds__(256) void lstm_seq_kernel(
    const float* __restrict__ x,      // [B, T, 4]
    const float* __restrict__ W_ih,   // [256, 4]
    const float* __restrict__ W_hh,   // [256, 49]
    const float* __restrict__ b_ih,   // [256]
    const float* __restrict__ b_hh,   // [256]
    const float* __restrict__ W_hr,   // [49, 64]
    const float* __restrict__ W_out,  // [49, 49]
    const float* __restrict__ b_out,  // [49]
    float* __restrict__ out)          // [B, 49]
{
    const int tid = threadIdx.x;
    const int b   = blockIdx.x;

    __shared__ float h_lds[52];          // padded to 52; [49..51] stay 0
    __shared__ float gates[NG];
    __shared__ float hfull[HID];
    __shared__ float part[NPROJ][4];     // projection partial sums
    __shared__ float x_lds[XCH * NIN];   // 64 timesteps of x for this batch

    // ---- per-thread resident weights ----
    const float4 wih = *reinterpret_cast<const float4*>(W_ih + tid * NIN);
    const float  bg  = b_ih[tid] + b_hh[tid];

    float whh[52];
    #pragma unroll
    for (int k = 0; k < 52; ++k)
        whh[k] = (k < 49) ? W_hh[tid * 49 + k] : 0.0f;

    // projection weights: thread tid<196 -> p=tid>>2 owns 16-wide slice jg=tid&3
    float whr[16];
    if (tid < 196) {
        const int p = tid >> 2, jg = tid & 3;
        #pragma unroll
        for (int jj = 0; jj < 16; ++jj)
            whr[jj] = W_hr[p * HID + jg * 16 + jj];
    }

    float c = 0.0f;                      // cell state, valid for tid<64

    if (tid < 52) h_lds[tid] = 0.0f;
    __syncthreads();

    for (int t = 0; t < T_STEPS; ++t) {
        // ---- stage 64 timesteps of x (coalesced, once per 64 steps) ----
        if ((t & (XCH - 1)) == 0) {
            x_lds[tid] = x[b * (T_STEPS * NIN) + t * NIN + tid];
            __syncthreads();
        }

        // ---- gate phase: all 256 threads, one gate each ----
        const float4 xv = *reinterpret_cast<const float4*>(x_lds + (t & (XCH - 1)) * NIN);
        float acc = bg + wih.x * xv.x + wih.y * xv.y + wih.z * xv.z + wih.w * xv.w;
        #pragma unroll
        for (int k = 0; k < 52; k += 4) {
            const float4 hv = *reinterpret_cast<const float4*>(h_lds + k);
            acc += whh[k] * hv.x + whh[k + 1] * hv.y
                 + whh[k + 2] * hv.z + whh[k + 3] * hv.w;
        }
        float a;
        if ((tid >> 6) == 2) {                       // g gate -> tanh
            const float e = __expf(2.0f * acc);
            a = 1.0f - __fdividef(2.0f, e + 1.0f);
        } else {                                     // i, f, o -> sigmoid
            a = __fdividef(1.0f, 1.0f + __expf(-acc));
        }
        gates[tid] = a;
        __syncthreads();

        // ---- cell update: threads 0..63 ----
        if (tid < HID) {
            const float gi = gates[tid];
            const float gf = gates[64 + tid];
            const float gg = gates[128 + tid];
            const float go = gates[192 + tid];
            c = gf * c + gi * gg;
            const float e  = __expf(2.0f * c);
            const float th = 1.0f - __fdividef(2.0f, e + 1.0f);
            hfull[tid] = go * th;
        }
        __syncthreads();

        // ---- projection partials: threads 0..195 (p = tid>>2, jg = tid&3) ----
        if (tid < 196) {
            const int jg = tid & 3;
            float s = 0.0f;
            #pragma unroll
            for (int jj = 0; jj < 16; jj += 4) {
                const float4 hv = *reinterpret_cast<const float4*>(hfull + jg * 16 + jj);
                s += whr[jj] * hv.x + whr[jj + 1] * hv.y
                   + whr[jj + 2] * hv.z + whr[jj + 3] * hv.w;
            }
            part[tid >> 2][jg] = s;
        }
        __syncthreads();

        // ---- projection reduce: threads 0..48 write new h ----
        if (tid < NPROJ) {
            const float4 pv = *reinterpret_cast<const float4*>(&part[tid][0]);
            h_lds[tid] = pv.x + pv.y + pv.z + pv.w;
        }
        __syncthreads();
    }

    // ---- epilogue: out = h_last @ W_out.T + b_out ----
    if (tid < NPROJ) {
        float s = b_out[tid];
        #pragma unroll
        for (int p = 0; p < NPROJ; ++p)
            s += h_lds[p] * W_out[tid * NPROJ + p];
        out[b * NPROJ + tid] = s;
    }
}

extern "C" void kernel_launch(void* const* d_in, const int* in_sizes, int n_in,
                              void* d_out, int out_size, void* d_ws, size_t ws_size,
                              hipStream_t stream) {
    (void)in_sizes; (void)n_in; (void)d_ws; (void)ws_size; (void)out_size;
    const float* x     = (const float*)d_in[0];
    const float* W_ih  = (const float*)d_in[1];
    const float* W_hh  = (const float*)d_in[2];
    const float* b_ih  = (const float*)d_in[3];
    const float* b_hh  = (const float*)d_in[4];
    const float* W_hr  = (const float*)d_in[5];
    const float* W_out = (const float*)d_in[6];
    const float* b_out = (const float*)d_in[7];
    float* out = (float*)d_out;

    lstm_seq_kernel<<<dim3(2048), dim3(256), 0, stream>>>(
        x, W_ih, W_hh, b_ih, b_hh, W_hr, W_out, b_out, out);
}

// Round 2
// 901.159 us; speedup vs baseline: 1.0493x; 1.0493x over previous
//
#include <hip/hip_runtime.h>

#define T_STEPS 512
#define NIN     4
#define HID     64
#define NPROJ   49
#define NG      256   // 4*HID
#define XCH     64    // x-chunk timesteps staged in LDS

// Pin a value into a VGPR: makes it opaque to LLVM so it cannot be
// rematerialized by re-loading from (const) memory inside the t-loop.
#define KEEP1(v)  asm volatile("" : "+v"(v))
#define KEEP4(v)  asm volatile("" : "+v"(v.x), "+v"(v.y), "+v"(v.z), "+v"(v.w))

__device__ __forceinline__ float fast_sigmoid(float x) {
    return __builtin_amdgcn_rcpf(1.0f + __expf(-x));
}
__device__ __forceinline__ float fast_tanh(float x) {
    // tanh(x) = 1 - 2/(exp(2x)+1)
    return 1.0f - 2.0f * __builtin_amdgcn_rcpf(__expf(2.0f * x) + 1.0f);
}

// One workgroup (256 threads) owns one batch element for the full T loop.
// Thread tid owns gate tid: W_hh row (12 float4 + 1 scalar), W_ih row and
// bias are FORCED register-resident. h (49), gates (256), h_full (64) are
// exchanged through LDS each timestep.
__global__ __launch_bounds__(256, 4) void lstm_seq_kernel(
    const float* __restrict__ x,      // [B, T, 4]
    const float* __restrict__ W_ih,   // [256, 4]
    const float* __restrict__ W_hh,   // [256, 49]
    const float* __restrict__ b_ih,   // [256]
    const float* __restrict__ b_hh,   // [256]
    const float* __restrict__ W_hr,   // [49, 64]
    const float* __restrict__ W_out,  // [49, 49]
    const float* __restrict__ b_out,  // [49]
    float* __restrict__ out)          // [B, 49]
{
    const int tid = threadIdx.x;
    const int b   = blockIdx.x;

    __shared__ float h_lds[52];          // padded; [49..51] stay 0
    __shared__ float gates[NG];
    __shared__ float hfull[HID];
    __shared__ float part[NPROJ][4];     // projection partial sums
    __shared__ float x_lds[XCH * NIN];   // 64 timesteps of x for this batch

    // ---- per-thread resident weights (forced into VGPRs) ----
    float4 wih = *reinterpret_cast<const float4*>(W_ih + tid * NIN);
    float  bg  = b_ih[tid] + b_hh[tid];
    KEEP4(wih); KEEP1(bg);

    const float* wrow = W_hh + tid * 49;
    float4 w0  = *reinterpret_cast<const float4*>(wrow + 0);
    float4 w1  = *reinterpret_cast<const float4*>(wrow + 4);
    float4 w2  = *reinterpret_cast<const float4*>(wrow + 8);
    float4 w3  = *reinterpret_cast<const float4*>(wrow + 12);
    float4 w4  = *reinterpret_cast<const float4*>(wrow + 16);
    float4 w5  = *reinterpret_cast<const float4*>(wrow + 20);
    float4 w6  = *reinterpret_cast<const float4*>(wrow + 24);
    float4 w7  = *reinterpret_cast<const float4*>(wrow + 28);
    float4 w8  = *reinterpret_cast<const float4*>(wrow + 32);
    float4 w9  = *reinterpret_cast<const float4*>(wrow + 36);
    float4 w10 = *reinterpret_cast<const float4*>(wrow + 40);
    float4 w11 = *reinterpret_cast<const float4*>(wrow + 44);
    float  w48 = wrow[48];               // scalar tail: avoids OOB float4 on last row
    KEEP4(w0); KEEP4(w1); KEEP4(w2);  KEEP4(w3);
    KEEP4(w4); KEEP4(w5); KEEP4(w6);  KEEP4(w7);
    KEEP4(w8); KEEP4(w9); KEEP4(w10); KEEP4(w11);
    KEEP1(w48);

    // projection weights: thread tid<196 -> p=tid>>2 owns 16-wide slice jg=tid&3
    float4 whrA, whrB, whrC, whrD;
    if (tid < 196) {
        const float* r = W_hr + (tid >> 2) * HID + (tid & 3) * 16;
        whrA = *reinterpret_cast<const float4*>(r + 0);
        whrB = *reinterpret_cast<const float4*>(r + 4);
        whrC = *reinterpret_cast<const float4*>(r + 8);
        whrD = *reinterpret_cast<const float4*>(r + 12);
        KEEP4(whrA); KEEP4(whrB); KEEP4(whrC); KEEP4(whrD);
    }

    float c = 0.0f;                      // cell state, valid for tid<64

    if (tid < 52) h_lds[tid] = 0.0f;
    __syncthreads();

    for (int t = 0; t < T_STEPS; ++t) {
        // ---- stage 64 timesteps of x (coalesced, once per 64 steps) ----
        if ((t & (XCH - 1)) == 0) {
            x_lds[tid] = x[b * (T_STEPS * NIN) + t * NIN + tid];
            __syncthreads();
        }

        // ---- gate phase: all 256 threads, one gate each ----
        const float4 xv = *reinterpret_cast<const float4*>(x_lds + (t & (XCH - 1)) * NIN);
        float acc = bg + wih.x * xv.x + wih.y * xv.y + wih.z * xv.z + wih.w * xv.w;

        const float4* hv = reinterpret_cast<const float4*>(h_lds);
        float4 h0 = hv[0], h1 = hv[1], h2 = hv[2],  h3 = hv[3];
        float4 h4 = hv[4], h5 = hv[5], h6 = hv[6],  h7 = hv[7];
        float4 h8 = hv[8], h9 = hv[9], h10 = hv[10], h11 = hv[11];
        float h48 = h_lds[48];
        acc += w0.x*h0.x + w0.y*h0.y + w0.z*h0.z + w0.w*h0.w;
        acc += w1.x*h1.x + w1.y*h1.y + w1.z*h1.z + w1.w*h1.w;
        acc += w2.x*h2.x + w2.y*h2.y + w2.z*h2.z + w2.w*h2.w;
        acc += w3.x*h3.x + w3.y*h3.y + w3.z*h3.z + w3.w*h3.w;
        acc += w4.x*h4.x + w4.y*h4.y + w4.z*h4.z + w4.w*h4.w;
        acc += w5.x*h5.x + w5.y*h5.y + w5.z*h5.z + w5.w*h5.w;
        acc += w6.x*h6.x + w6.y*h6.y + w6.z*h6.z + w6.w*h6.w;
        acc += w7.x*h7.x + w7.y*h7.y + w7.z*h7.z + w7.w*h7.w;
        acc += w8.x*h8.x + w8.y*h8.y + w8.z*h8.z + w8.w*h8.w;
        acc += w9.x*h9.x + w9.y*h9.y + w9.z*h9.z + w9.w*h9.w;
        acc += w10.x*h10.x + w10.y*h10.y + w10.z*h10.z + w10.w*h10.w;
        acc += w11.x*h11.x + w11.y*h11.y + w11.z*h11.z + w11.w*h11.w;
        acc += w48 * h48;

        const float a = ((tid >> 6) == 2) ? fast_tanh(acc) : fast_sigmoid(acc);
        gates[tid] = a;
        __syncthreads();

        // ---- cell update: threads 0..63 ----
        if (tid < HID) {
            const float gi = gates[tid];
            const float gf = gates[64 + tid];
            const float gg = gates[128 + tid];
            const float go = gates[192 + tid];
            c = gf * c + gi * gg;
            hfull[tid] = go * fast_tanh(c);
        }
        __syncthreads();

        // ---- projection partials: threads 0..195 (p = tid>>2, jg = tid&3) ----
        if (tid < 196) {
            const int jg = tid & 3;
            const float4* fv = reinterpret_cast<const float4*>(hfull + jg * 16);
            const float4 f0 = fv[0], f1 = fv[1], f2 = fv[2], f3 = fv[3];
            float s;
            s  = whrA.x*f0.x + whrA.y*f0.y + whrA.z*f0.z + whrA.w*f0.w;
            s += whrB.x*f1.x + whrB.y*f1.y + whrB.z*f1.z + whrB.w*f1.w;
            s += whrC.x*f2.x + whrC.y*f2.y + whrC.z*f2.z + whrC.w*f2.w;
            s += whrD.x*f3.x + whrD.y*f3.y + whrD.z*f3.z + whrD.w*f3.w;
            part[tid >> 2][jg] = s;
        }
        __syncthreads();

        // ---- projection reduce: threads 0..48 write new h ----
        if (tid < NPROJ) {
            const float4 pv = *reinterpret_cast<const float4*>(&part[tid][0]);
            h_lds[tid] = pv.x + pv.y + pv.z + pv.w;
        }
        __syncthreads();
    }

    // ---- epilogue: out = h_last @ W_out.T + b_out ----
    if (tid < NPROJ) {
        float s = b_out[tid];
        #pragma unroll
        for (int p = 0; p < NPROJ; ++p)
            s += h_lds[p] * W_out[tid * NPROJ + p];
        out[b * NPROJ + tid] = s;
    }
}

extern "C" void kernel_launch(void* const* d_in, const int* in_sizes, int n_in,
                              void* d_out, int out_size, void* d_ws, size_t ws_size,
                              hipStream_t stream) {
    (void)in_sizes; (void)n_in; (void)d_ws; (void)ws_size; (void)out_size;
    const float* x     = (const float*)d_in[0];
    const float* W_ih  = (const float*)d_in[1];
    const float* W_hh  = (const float*)d_in[2];
    const float* b_ih  = (const float*)d_in[3];
    const float* b_hh  = (const float*)d_in[4];
    const float* W_hr  = (const float*)d_in[5];
    const float* W_out = (const float*)d_in[6];
    const float* b_out = (const float*)d_in[7];
    float* out = (float*)d_out;

    lstm_seq_kernel<<<dim3(2048), dim3(256), 0, stream>>>(
        x, W_ih, W_hh, b_ih, b_hh, W_hr, W_out, b_out, out);
}

// Round 3
// 860.090 us; speedup vs baseline: 1.0994x; 1.0477x over previous
//
#include <hip/hip_runtime.h>

#define T_STEPS 512
#define NIN     4
#define HID     64
#define NPROJ   49

// Pin a scalar into a VGPR (defeats rematerialization).
#define KEEP1(v)  asm volatile("" : "+v"(v))

__device__ __forceinline__ float fast_sigmoid(float x) {
    return __builtin_amdgcn_rcpf(1.0f + __expf(-x));
}
__device__ __forceinline__ float fast_tanh(float x) {
    // tanh(x) = 1 - 2/(exp(2x)+1)
    return 1.0f - 2.0f * __builtin_amdgcn_rcpf(__expf(2.0f * x) + 1.0f);
}

// One WAVE (64 threads) per batch element. Lane j owns hidden index j:
// it holds all four W_hh gate rows (i,f,g,o) for index j in registers,
// computes the four gate dots against the LDS-broadcast h, updates c_j
// locally, and writes h_full[j] to LDS. Projection h_new = W_hr @ h_full
// reads W_hr transposed from LDS (conflict-free, zero VGPR cost).
// No inter-wave synchronization exists: every block is one wave.
__global__ __launch_bounds__(64, 2) void lstm_wave_kernel(
    const float* __restrict__ x,      // [B, T, 4]
    const float* __restrict__ W_ih,   // [256, 4]
    const float* __restrict__ W_hh,   // [256, 49]
    const float* __restrict__ b_ih,   // [256]
    const float* __restrict__ b_hh,   // [256]
    const float* __restrict__ W_hr,   // [49, 64]
    const float* __restrict__ W_out,  // [49, 49]
    const float* __restrict__ b_out,  // [49]
    float* __restrict__ out)          // [B, 49]
{
    const int j = threadIdx.x;        // hidden index 0..63
    const int b = blockIdx.x;

    __shared__ __align__(16) float Wt[HID][52];   // Wt[k][p] = W_hr[p][k]
    __shared__ __align__(16) float h_lds[52];     // [49..51] stay 0
    __shared__ __align__(16) float hf_lds[HID];
    __shared__ __align__(16) float x_lds[64 * NIN];

    // ---- stage W_hr transposed (each p-iter is a coalesced 256B read) ----
    #pragma unroll 7
    for (int p = 0; p < NPROJ; ++p)
        Wt[j][p] = W_hr[p * HID + j];
    if (j < 52) h_lds[j] = 0.0f;

    // ---- per-lane register-resident weights ----
    const float* r0 = W_hh + (0 * HID + j) * NPROJ;   // i row
    const float* r1 = W_hh + (1 * HID + j) * NPROJ;   // f row
    const float* r2 = W_hh + (2 * HID + j) * NPROJ;   // g row
    const float* r3 = W_hh + (3 * HID + j) * NPROJ;   // o row
    float wI[NPROJ], wF[NPROJ], wG[NPROJ], wO[NPROJ];
    #pragma unroll
    for (int k = 0; k < NPROJ; ++k) {
        wI[k] = r0[k]; wF[k] = r1[k]; wG[k] = r2[k]; wO[k] = r3[k];
        KEEP1(wI[k]); KEEP1(wF[k]); KEEP1(wG[k]); KEEP1(wO[k]);
    }

    float uI[NIN], uF[NIN], uG[NIN], uO[NIN];
    #pragma unroll
    for (int k = 0; k < NIN; ++k) {
        uI[k] = W_ih[(0 * HID + j) * NIN + k];
        uF[k] = W_ih[(1 * HID + j) * NIN + k];
        uG[k] = W_ih[(2 * HID + j) * NIN + k];
        uO[k] = W_ih[(3 * HID + j) * NIN + k];
        KEEP1(uI[k]); KEEP1(uF[k]); KEEP1(uG[k]); KEEP1(uO[k]);
    }
    float bI = b_ih[0 * HID + j] + b_hh[0 * HID + j];
    float bF = b_ih[1 * HID + j] + b_hh[1 * HID + j];
    float bG = b_ih[2 * HID + j] + b_hh[2 * HID + j];
    float bO = b_ih[3 * HID + j] + b_hh[3 * HID + j];
    KEEP1(bI); KEEP1(bF); KEEP1(bG); KEEP1(bO);

    const int pj = (j < NPROJ) ? j : 0;   // clamp: lanes 49-63 read col 0 (discarded)
    float c = 0.0f;
    __syncthreads();

    for (int t = 0; t < T_STEPS; ++t) {
        // ---- stage 64 timesteps of x (one coalesced float4 per lane) ----
        if ((t & 63) == 0) {
            reinterpret_cast<float4*>(x_lds)[j] =
                reinterpret_cast<const float4*>(x)[b * T_STEPS + t + j];
            __syncthreads();
        }
        const float4 xv = reinterpret_cast<const float4*>(x_lds)[t & 63];

        // ---- four gate dots, h broadcast from LDS (reused 4x per read) ----
        float aI = bI + uI[0]*xv.x + uI[1]*xv.y + uI[2]*xv.z + uI[3]*xv.w;
        float aF = bF + uF[0]*xv.x + uF[1]*xv.y + uF[2]*xv.z + uF[3]*xv.w;
        float aG = bG + uG[0]*xv.x + uG[1]*xv.y + uG[2]*xv.z + uG[3]*xv.w;
        float aO = bO + uO[0]*xv.x + uO[1]*xv.y + uO[2]*xv.z + uO[3]*xv.w;
        #pragma unroll
        for (int k4 = 0; k4 < 12; ++k4) {
            const float4 hv = reinterpret_cast<const float4*>(h_lds)[k4];
            const int k = 4 * k4;
            aI += wI[k]*hv.x + wI[k+1]*hv.y + wI[k+2]*hv.z + wI[k+3]*hv.w;
            aF += wF[k]*hv.x + wF[k+1]*hv.y + wF[k+2]*hv.z + wF[k+3]*hv.w;
            aG += wG[k]*hv.x + wG[k+1]*hv.y + wG[k+2]*hv.z + wG[k+3]*hv.w;
            aO += wO[k]*hv.x + wO[k+1]*hv.y + wO[k+2]*hv.z + wO[k+3]*hv.w;
        }
        const float h48 = h_lds[48];
        aI += wI[48]*h48; aF += wF[48]*h48; aG += wG[48]*h48; aO += wO[48]*h48;

        // ---- nonlinearities + lane-local cell update ----
        const float gi = fast_sigmoid(aI);
        const float gf = fast_sigmoid(aF);
        const float gg = fast_tanh(aG);
        const float go = fast_sigmoid(aO);
        c = gf * c + gi * gg;
        hf_lds[j] = go * fast_tanh(c);
        __syncthreads();

        // ---- projection: h_new[p] = sum_k hf[k] * Wt[k][p] ----
        float s = 0.0f;
        #pragma unroll
        for (int k4 = 0; k4 < 16; ++k4) {
            const float4 hv = reinterpret_cast<const float4*>(hf_lds)[k4];
            const int k = 4 * k4;
            s += hv.x * Wt[k + 0][pj];
            s += hv.y * Wt[k + 1][pj];
            s += hv.z * Wt[k + 2][pj];
            s += hv.w * Wt[k + 3][pj];
        }
        if (j < NPROJ) h_lds[j] = s;   // in-order DS: next step's reads see it
        __syncthreads();
    }

    // ---- epilogue: out = h_last @ W_out.T + b_out ----
    if (j < NPROJ) {
        float s2 = b_out[j];
        #pragma unroll 7
        for (int p = 0; p < NPROJ; ++p)
            s2 += h_lds[p] * W_out[j * NPROJ + p];
        out[b * NPROJ + j] = s2;
    }
}

extern "C" void kernel_launch(void* const* d_in, const int* in_sizes, int n_in,
                              void* d_out, int out_size, void* d_ws, size_t ws_size,
                              hipStream_t stream) {
    (void)in_sizes; (void)n_in; (void)d_ws; (void)ws_size; (void)out_size;
    const float* x     = (const float*)d_in[0];
    const float* W_ih  = (const float*)d_in[1];
    const float* W_hh  = (const float*)d_in[2];
    const float* b_ih  = (const float*)d_in[3];
    const float* b_hh  = (const float*)d_in[4];
    const float* W_hr  = (const float*)d_in[5];
    const float* W_out = (const float*)d_in[6];
    const float* b_out = (const float*)d_in[7];
    float* out = (float*)d_out;

    lstm_wave_kernel<<<dim3(2048), dim3(64), 0, stream>>>(
        x, W_ih, W_hh, b_ih, b_hh, W_hr, W_out, b_out, out);
}

// Round 4
// 361.987 us; speedup vs baseline: 2.6122x; 2.3760x over previous
//
#include <hip/hip_runtime.h>

#define TSTEPS 512
#define BPB    16                 // batch elements per block
#define ROWB   320                // bytes per A row (160 k-slots * 2B)
#define ABYTES (16 * ROWB)        // 5120 = 40*128 (swizzle-safe)

typedef short bf16x8 __attribute__((ext_vector_type(8)));
typedef float f32x4  __attribute__((ext_vector_type(4)));

__device__ __forceinline__ float fast_sigmoid(float x) {
    return __builtin_amdgcn_rcpf(1.0f + __expf(-x));
}
__device__ __forceinline__ float fast_tanh(float x) {
    return 1.0f - 2.0f * __builtin_amdgcn_rcpf(__expf(2.0f * x) + 1.0f);
}
// float -> bf16 (RTN-even) on raw bits; values here are finite (no NaN path).
__device__ __forceinline__ unsigned int f2bf(float f) {
    unsigned int u = __builtin_bit_cast(unsigned int, f);
    return (u + 0x7FFFu + ((u >> 16) & 1u)) >> 16;
}
__device__ __forceinline__ float bf2f(unsigned int us) {
    return __builtin_bit_cast(float, us << 16);
}
// pack (hi,lo) bf16 split of f into one dword (hi = low half = even k-slot)
__device__ __forceinline__ unsigned int split_pack(float f) {
    unsigned int hi = f2bf(f);
    unsigned int lo = f2bf(f - bf2f(hi));
    return hi | (lo << 16);
}

// gates = [hf_hi/lo interleaved (128 slots) | x_hi/lo (8) | 1 (slot 136) | 0pad] @ B
// B rows 2h,2h+1 = M[h][n] where M = W_hr^T W_hh^T (projection composed away);
// rows 128+2c,129+2c = W_ih[n][c]; row 136 = b_ih[n]+b_hh[n].
// Block: 4 waves, 16 batches. Wave w owns hid chunk w*16..w*16+15 for all 4 gate
// types (4 N-tiles x 5 K-steps = 20 mfma_16x16x32_bf16 per step). Cell state is
// lane-local. A operand double-buffered in LDS, XOR-swizzled, 1 barrier/step.
__global__ __launch_bounds__(256, 1) void lstm_mfma_kernel(
    const float* __restrict__ x,      // [B, T, 4]
    const float* __restrict__ W_ih,   // [256, 4]
    const float* __restrict__ W_hh,   // [256, 49]
    const float* __restrict__ b_ih,   // [256]
    const float* __restrict__ b_hh,   // [256]
    const float* __restrict__ W_hr,   // [49, 64]
    const float* __restrict__ W_out,  // [49, 49]
    const float* __restrict__ b_out,  // [49]
    float* __restrict__ out)          // [B, 49]
{
    const int tid = threadIdx.x;
    const int w   = tid >> 6;         // wave 0..3 -> hid chunk
    const int l   = tid & 63;
    const int g4  = l >> 4;           // lane k-group 0..3
    const int ln  = l & 15;           // M-row (A) / N-col (B,C)
    const int b0  = blockIdx.x * BPB;

    __shared__ __align__(128) unsigned char Abuf[2 * ABYTES];
    __shared__ __align__(16)  float hf32[BPB][64];
    __shared__ float hproj[BPB][52];

    // ---------------- prologue ----------------
    for (int i = tid; i < (2 * ABYTES) / 4; i += 256)
        ((unsigned int*)Abuf)[i] = 0u;
    __syncthreads();

    // Composed recurrent matrix M[h][n] = sum_p W_hr[p][h] * W_hh[n][p],
    // for this lane's 16 h-values (h = s*16 + g4*4 + jp) and 4 n-columns.
    float Msum[4][16];
    #pragma unroll
    for (int t4 = 0; t4 < 4; ++t4)
        #pragma unroll
        for (int i = 0; i < 16; ++i) Msum[t4][i] = 0.0f;

    for (int p = 0; p < 49; ++p) {
        float wr[16];
        #pragma unroll
        for (int s = 0; s < 4; ++s)
            #pragma unroll
            for (int jp = 0; jp < 4; ++jp)
                wr[s * 4 + jp] = W_hr[p * 64 + s * 16 + g4 * 4 + jp];
        #pragma unroll
        for (int t4 = 0; t4 < 4; ++t4) {
            const float whh = W_hh[(t4 * 64 + w * 16 + ln) * 49 + p];
            #pragma unroll
            for (int i = 0; i < 16; ++i) Msum[t4][i] += whh * wr[i];
        }
    }

    // Build resident B-fragments: Bf[tile][kstep], element j = k-slot s*32+g4*8+j.
    bf16x8 Bf[4][5];
    union U { unsigned int d[4]; bf16x8 v; };
    #pragma unroll
    for (int t4 = 0; t4 < 4; ++t4) {
        #pragma unroll
        for (int s = 0; s < 4; ++s) {
            U u;
            #pragma unroll
            for (int jp = 0; jp < 4; ++jp) {
                const unsigned int us = f2bf(Msum[t4][s * 4 + jp]);
                u.d[jp] = us | (us << 16);       // hi-slot and lo-slot share M row
            }
            Bf[t4][s] = u.v;
        }
        U u; u.d[0] = u.d[1] = u.d[2] = u.d[3] = 0u;
        const int n = t4 * 64 + w * 16 + ln;
        if (g4 == 0) {                            // slots 128..135: x columns
            #pragma unroll
            for (int c = 0; c < 4; ++c) {
                const unsigned int us = f2bf(W_ih[n * 4 + c]);
                u.d[c] = us | (us << 16);
            }
        } else if (g4 == 1) {                     // slot 136: bias column
            u.d[0] = f2bf(b_ih[n] + b_hh[n]);
        }
        Bf[t4][4] = u.v;
    }

    // x_0 into A[0]; constant-1 bias column into both buffers.
    const int xbase = (b0 + (l >> 2)) * (TSTEPS * 4) + (l & 3);
    if (w == 0) {
        const float xv = x[xbase];
        const int row  = l >> 2;
        const int byte = (row * ROWB + 256 + 4 * (l & 3)) ^ ((row & 7) << 4);
        *(unsigned int*)(Abuf + byte) = split_pack(xv);
    }
    if (tid < 32) {
        const int row = tid & 15, buf = tid >> 4;
        const int byte = (row * ROWB + 272) ^ ((row & 7) << 4);
        *(unsigned int*)(Abuf + buf * ABYTES + byte) = 0x3F80u;   // bf16(1.0), lo=0
    }
    __syncthreads();

    // Hoisted per-lane addresses.
    int aoff[5];
    #pragma unroll
    for (int s = 0; s < 5; ++s)
        aoff[s] = (ln * ROWB + s * 64 + g4 * 16) ^ ((ln & 7) << 4);
    int woff[4];
    #pragma unroll
    for (int r = 0; r < 4; ++r) {
        const int row = g4 * 4 + r;
        woff[r] = (row * ROWB + 4 * (w * 16 + ln)) ^ ((row & 7) << 4);
    }
    const int xwoff = ((l >> 2) * ROWB + 256 + 4 * (l & 3)) ^ (((l >> 2) & 7) << 4);

    float cst[4] = {0.f, 0.f, 0.f, 0.f};
    float hffin[4];
    int cur = 0;

    // ---------------- recurrence ----------------
    for (int t = 0; t < TSTEPS; ++t) {
        // prefetch x_{t+1} (wave 0) — consumed ~500 cyc later at the write phase
        float xnext = 0.0f;
        if (w == 0) {
            const int tt = (t + 1 < TSTEPS) ? t + 1 : TSTEPS - 1;
            xnext = x[xbase + 4 * tt];
        }

        const unsigned char* Ab = Abuf + cur * ABYTES;
        bf16x8 af[5];
        #pragma unroll
        for (int s = 0; s < 5; ++s)
            af[s] = *(const bf16x8*)(Ab + aoff[s]);

        f32x4 aI = {0.f, 0.f, 0.f, 0.f}, aF = aI, aG = aI, aO = aI;
        #pragma unroll
        for (int s = 0; s < 5; ++s) {
            aI = __builtin_amdgcn_mfma_f32_16x16x32_bf16(af[s], Bf[0][s], aI, 0, 0, 0);
            aF = __builtin_amdgcn_mfma_f32_16x16x32_bf16(af[s], Bf[1][s], aF, 0, 0, 0);
            aG = __builtin_amdgcn_mfma_f32_16x16x32_bf16(af[s], Bf[2][s], aG, 0, 0, 0);
            aO = __builtin_amdgcn_mfma_f32_16x16x32_bf16(af[s], Bf[3][s], aO, 0, 0, 0);
        }

        unsigned char* An = Abuf + (cur ^ 1) * ABYTES;
        #pragma unroll
        for (int r = 0; r < 4; ++r) {
            const float gi = fast_sigmoid(aI[r]);
            const float gf = fast_sigmoid(aF[r]);
            const float gg = fast_tanh(aG[r]);
            const float go = fast_sigmoid(aO[r]);
            cst[r] = gf * cst[r] + gi * gg;
            const float hf = go * fast_tanh(cst[r]);
            hffin[r] = hf;
            *(unsigned int*)(An + woff[r]) = split_pack(hf);
        }
        if (w == 0)
            *(unsigned int*)(An + xwoff) = split_pack(xnext);

        __syncthreads();
        cur ^= 1;
    }

    // ---------------- epilogue (exact fp32, two-stage like reference) ----------------
    #pragma unroll
    for (int r = 0; r < 4; ++r)
        hf32[g4 * 4 + r][w * 16 + ln] = hffin[r];
    __syncthreads();

    for (int idx = tid; idx < BPB * 49; idx += 256) {
        const int bb = idx / 49, q = idx - bb * 49;
        float s = 0.0f;
        #pragma unroll 8
        for (int h = 0; h < 64; ++h) s += hf32[bb][h] * W_hr[q * 64 + h];
        hproj[bb][q] = s;
    }
    __syncthreads();
    for (int idx = tid; idx < BPB * 49; idx += 256) {
        const int bb = idx / 49, q2 = idx - bb * 49;
        float s = b_out[q2];
        #pragma unroll 7
        for (int p = 0; p < 49; ++p) s += hproj[bb][p] * W_out[q2 * 49 + p];
        out[(b0 + bb) * 49 + q2] = s;
    }
}

extern "C" void kernel_launch(void* const* d_in, const int* in_sizes, int n_in,
                              void* d_out, int out_size, void* d_ws, size_t ws_size,
                              hipStream_t stream) {
    (void)in_sizes; (void)n_in; (void)d_ws; (void)ws_size; (void)out_size;
    const float* x     = (const float*)d_in[0];
    const float* W_ih  = (const float*)d_in[1];
    const float* W_hh  = (const float*)d_in[2];
    const float* b_ih  = (const float*)d_in[3];
    const float* b_hh  = (const float*)d_in[4];
    const float* W_hr  = (const float*)d_in[5];
    const float* W_out = (const float*)d_in[6];
    const float* b_out = (const float*)d_in[7];
    float* outp = (float*)d_out;

    lstm_mfma_kernel<<<dim3(2048 / BPB), dim3(256), 0, stream>>>(
        x, W_ih, W_hh, b_ih, b_hh, W_hr, W_out, b_out, outp);
}